// Round 1
// baseline (389.122 us; speedup 1.0000x reference)
//
#include <hip/hip_runtime.h>
#include <hip/hip_bf16.h>

#define EMB 300
#define HID 10
#define BATCH 256
#define SEQ 512
#define ROWS (BATCH * SEQ)   // 131072
#define G3 (3 * HID)         // 30

// fast sigmoid / tanh via hardware exp2/rcp (plenty of precision for 2.75e-2 abs threshold)
__device__ __forceinline__ float fsig(float x) {
    float e = __builtin_amdgcn_exp2f(-1.4426950408889634f * x);
    return __builtin_amdgcn_rcpf(1.0f + e);
}
__device__ __forceinline__ float ftanh(float x) {
    // tanh(x) = 1 - 2/(exp(2x)+1)
    float e = __builtin_amdgcn_exp2f(2.8853900817779268f * x);
    return fmaf(-2.0f, __builtin_amdgcn_rcpf(1.0f + e), 1.0f);
}

__device__ __forceinline__ float rdlane(float v, int lane) {
    return __int_as_float(__builtin_amdgcn_readlane(__float_as_int(v), lane));
}

// ---------------------------------------------------------------------------
// Kernel 1: gi[g][row] = b_ih[g] + sum_e x[row][e] * w_ih[g][e]
// plane-major output [30][ROWS]: coalesced stores here, coalesced lane reads in k_scan.
// ---------------------------------------------------------------------------
__global__ __launch_bounds__(256) void k_gi(const float* __restrict__ x,
                                            const float* __restrict__ w_ih,
                                            const float* __restrict__ b_ih,
                                            float* __restrict__ gi) {
    __shared__ float ws[G3 * EMB]; // 36 KB
    for (int i = threadIdx.x; i < G3 * EMB; i += 256) ws[i] = w_ih[i];
    __syncthreads();

    const int r = blockIdx.x * 256 + threadIdx.x;     // row = b*SEQ + s
    const float* __restrict__ xr = x + (size_t)r * EMB;

    float acc[G3];
#pragma unroll
    for (int g = 0; g < G3; g++) acc[g] = b_ih[g];

    for (int k = 0; k < EMB; k += 4) {
        const float4 xv = *(const float4*)(xr + k);
#pragma unroll
        for (int g = 0; g < G3; g++) {
            const float4 wv = *(const float4*)(&ws[g * EMB + k]);
            acc[g] = fmaf(xv.x, wv.x, acc[g]);
            acc[g] = fmaf(xv.y, wv.y, acc[g]);
            acc[g] = fmaf(xv.z, wv.z, acc[g]);
            acc[g] = fmaf(xv.w, wv.w, acc[g]);
        }
    }
#pragma unroll
    for (int g = 0; g < G3; g++) gi[(size_t)g * ROWS + r] = acc[g];
}

// ---------------------------------------------------------------------------
// Kernel 2: backward direction = ONE GRU step on x[:, SEQ-1] with h0 = 0.
// One block (64 thr) per batch. Thread g<30 computes gate g's input projection.
// ---------------------------------------------------------------------------
__global__ __launch_bounds__(64) void k_back(const float* __restrict__ x,
                                             const float* __restrict__ w_ih_b,
                                             const float* __restrict__ b_ih_b,
                                             const float* __restrict__ b_hh_b,
                                             float* __restrict__ hb) {
    const int b = blockIdx.x;
    const int j = threadIdx.x;
    const int gc = j < G3 ? j : G3 - 1;

    const float* __restrict__ xr = x + ((size_t)b * SEQ + (SEQ - 1)) * EMB;
    const float* __restrict__ wr = w_ih_b + (size_t)gc * EMB;

    float acc = b_ih_b[gc];
    for (int k = 0; k < EMB; k += 4) {
        const float4 xv = *(const float4*)(xr + k);
        const float4 wv = *(const float4*)(wr + k);
        acc = fmaf(xv.x, wv.x, acc);
        acc = fmaf(xv.y, wv.y, acc);
        acc = fmaf(xv.z, wv.z, acc);
        acc = fmaf(xv.w, wv.w, acc);
    }
    // lanes 0..9: gather i_z (lane j+10) and i_n (lane j+20); h0=0 so gh = b_hh_b
    const int jc = j < HID ? j : 0;
    const float i_r = acc;
    const float i_z = __shfl(acc, jc + HID, 64);
    const float i_n = __shfl(acc, jc + 2 * HID, 64);
    const float r = fsig(i_r + b_hh_b[jc]);
    const float z = fsig(i_z + b_hh_b[HID + jc]);
    const float n = ftanh(fmaf(r, b_hh_b[2 * HID + jc], i_n));
    if (j < HID) hb[b * HID + j] = (1.0f - z) * n;
}

// ---------------------------------------------------------------------------
// Kernel 3: forward recurrence, one wave per batch element.
// Lane j (j<10) owns h[j]; computes r,z,n dots locally; h broadcast via
// v_readlane into SGPRs (uniform per wave). Fused final Linear at the end.
// ---------------------------------------------------------------------------
__global__ __launch_bounds__(64) void k_scan(const float* __restrict__ gi,
                                             const float* __restrict__ w_hh,
                                             const float* __restrict__ b_hh,
                                             const float* __restrict__ hb,
                                             const float* __restrict__ w_lin,
                                             const float* __restrict__ b_lin,
                                             float* __restrict__ out) {
    const int b = blockIdx.x;
    const int j = threadIdx.x;
    const int jc = j < HID ? j : HID - 1;   // clamp: lanes >=10 mirror lane 9 (ignored)

    float wr[HID], wz[HID], wn[HID];
#pragma unroll
    for (int k = 0; k < HID; k++) {
        wr[k] = w_hh[jc * HID + k];
        wz[k] = w_hh[(HID + jc) * HID + k];
        wn[k] = w_hh[(2 * HID + jc) * HID + k];
    }
    const float br = b_hh[jc];
    const float bz = b_hh[HID + jc];
    const float bn = b_hh[2 * HID + jc];

    const float* __restrict__ gr = gi + (size_t)jc * ROWS + (size_t)b * SEQ;
    const float* __restrict__ gz = gi + (size_t)(HID + jc) * ROWS + (size_t)b * SEQ;
    const float* __restrict__ gn = gi + (size_t)(2 * HID + jc) * ROWS + (size_t)b * SEQ;

    float h = 0.0f;
    float hs[HID];
#pragma unroll
    for (int k = 0; k < HID; k++) hs[k] = 0.0f;

    float ir = gr[0], iz = gz[0], in_ = gn[0];

    for (int t = 0; t < SEQ; t++) {
        const int tn = (t + 1 < SEQ) ? t + 1 : t;
        const float ir_n = gr[tn];      // prefetch next step's gi
        const float iz_n = gz[tn];
        const float in_n = gn[tn];

        float ar = ir + br;
        float az = iz + bz;
        float an = bn;
#pragma unroll
        for (int k = 0; k < HID; k++) {
            ar = fmaf(wr[k], hs[k], ar);
            az = fmaf(wz[k], hs[k], az);
            an = fmaf(wn[k], hs[k], an);
        }
        const float r = fsig(ar);
        const float z = fsig(az);
        const float n = ftanh(fmaf(r, an, in_));
        h = fmaf(z, h - n, n);          // (1-z)*n + z*h

        // broadcast new h[0..9] into wave-uniform (SGPR) values
#pragma unroll
        for (int k = 0; k < HID; k++) hs[k] = rdlane(h, k);

        ir = ir_n; iz = iz_n; in_ = in_n;
    }

    // fused Linear(2H -> 1): out[b] = sum_j wl[j]*hf[j] + wl[10+j]*hb[j] + b_lin
    const float hbv = hb[b * HID + jc];
    const float p = fmaf(w_lin[jc], h, w_lin[HID + jc] * hbv);
    float s = 0.0f;
#pragma unroll
    for (int k = 0; k < HID; k++) s += rdlane(p, k);
    if (j == 0) out[b] = s + b_lin[0];
}

// ---------------------------------------------------------------------------
extern "C" void kernel_launch(void* const* d_in, const int* in_sizes, int n_in,
                              void* d_out, int out_size, void* d_ws, size_t ws_size,
                              hipStream_t stream) {
    const float* x      = (const float*)d_in[0];
    const float* w_ih_f = (const float*)d_in[1];
    const float* w_hh_f = (const float*)d_in[2];
    const float* b_ih_f = (const float*)d_in[3];
    const float* b_hh_f = (const float*)d_in[4];
    const float* w_ih_b = (const float*)d_in[5];
    const float* w_hh_b = (const float*)d_in[6];   // unused: backward is a single step, h0=0
    const float* b_ih_b = (const float*)d_in[7];
    const float* b_hh_b = (const float*)d_in[8];
    const float* w_lin  = (const float*)d_in[9];
    const float* b_lin  = (const float*)d_in[10];
    float* out = (float*)d_out;

    float* gi = (float*)d_ws;                       // [30][ROWS] = 15.73 MB
    float* hb = gi + (size_t)G3 * ROWS;             // [BATCH][HID]
    (void)w_hh_b; (void)in_sizes; (void)n_in; (void)out_size; (void)ws_size;

    k_gi  <<<ROWS / 256, 256, 0, stream>>>(x, w_ih_f, b_ih_f, gi);
    k_back<<<BATCH,      64,  0, stream>>>(x, w_ih_b, b_ih_b, b_hh_b, hb);
    k_scan<<<BATCH,      64,  0, stream>>>(gi, w_hh_f, b_hh_f, hb, w_lin, b_lin, out);
}